// Round 14
// baseline (386.402 us; speedup 1.0000x reference)
//
#include <hip/hip_runtime.h>
#include <hip/hip_bf16.h>
#include <stdint.h>
#include <stddef.h>

#define BATCH 4096
#define INF   1024
#define OUTF  1024
#define KDIM  8192            // 1024 in-features * 8 spline bases
#define KS    4               // split-K factor
#define KSL   (KDIM / KS)     // 2048 per slice
#define BK    64
#define NT    (KSL / BK)      // 32 K-tiles per block

typedef __attribute__((ext_vector_type(8)))  short           short8;
typedef __attribute__((ext_vector_type(8)))  unsigned short  ushort8;
typedef __attribute__((ext_vector_type(4)))  float           f32x4;

// ---------------------------------------------------------------------------
// Fast closed-form cubic B-spline bases (uniform knots, grid gap 0.4,
// range [-2.2, 2.2)). Identical values to the reference recursion up to fp32
// rounding (~1e-6 abs, far below bf16 quantization). Out-of-range x -> all
// zero via the placement chain (i0 outside [-3,7] matches nothing).
// ---------------------------------------------------------------------------
__device__ __forceinline__ ushort8 bases8_fast(float xv) {
    const float X  = (xv + 2.2f) * 2.5f;      // cell space: knot(j) at X=j
    const float cf = floorf(X);
    const float t  = X - cf;                  // local coordinate in cell
    const int   c  = (int)cf;
    const float s  = 1.0f - t;
    const float t2 = t * t;
    const float w0 = s * s * s * (1.0f / 6.0f);
    const float w3 = t2 * t * (1.0f / 6.0f);
    const float w1 = (0.5f * t - 1.0f) * t2 + (2.0f / 3.0f);   // (3t^3-6t^2+4)/6
    const float w2 = 1.0f - w0 - w1 - w3;     // exact partition of unity

    __hip_bfloat16 h0 = __float2bfloat16(w0);
    __hip_bfloat16 h1 = __float2bfloat16(w1);
    __hip_bfloat16 h2 = __float2bfloat16(w2);
    __hip_bfloat16 h3 = __float2bfloat16(w3);
    const unsigned short u0 = *reinterpret_cast<unsigned short*>(&h0);
    const unsigned short u1 = *reinterpret_cast<unsigned short*>(&h1);
    const unsigned short u2 = *reinterpret_cast<unsigned short*>(&h2);
    const unsigned short u3 = *reinterpret_cast<unsigned short*>(&h3);

    const int i0 = c - 3;                     // first nonzero basis index
    union { ushort8 v; unsigned short u[8]; } pk;
#pragma unroll
    for (int g = 0; g < 8; ++g) {             // 11 distinct cmps (CSE) + selects
        unsigned short v = 0;
        v = (i0 == g    ) ? u0 : v;
        v = (i0 == g - 1) ? u1 : v;
        v = (i0 == g - 2) ? u2 : v;
        v = (i0 == g - 3) ? u3 : v;
        pk.u[g] = v;
    }
    return pk.v;
}

// ---------------------------------------------------------------------------
// Kernel 1: weight fp32 -> bf16 (B^T row-major over k = i*8+g already).
// ---------------------------------------------------------------------------
__global__ __launch_bounds__(256) void kan_wconv(const f32x4* __restrict__ w,
                                                 short8* __restrict__ Wb) {
    size_t idx = (size_t)blockIdx.x * 256 + threadIdx.x;
    f32x4 a = w[idx * 2];
    f32x4 c = w[idx * 2 + 1];
    float t[8] = {a[0], a[1], a[2], a[3], c[0], c[1], c[2], c[3]};
    union { short8 v; unsigned short u[8]; } pk;
#pragma unroll
    for (int g = 0; g < 8; ++g) {
        __hip_bfloat16 h = __float2bfloat16(t[g]);
        pk.u[g] = *reinterpret_cast<unsigned short*>(&h);
    }
    Wb[idx] = pk.v;
}

// ---------------------------------------------------------------------------
// Kernel 2: FUSED bases + bf16 GEMM (r11 structure, A generated in-kernel).
// 256x256 tile, BK=64, split-K=4, double-buffer (128 KiB), 1024 threads =
// 16 waves (4M x 4N, 64x64/wave), mfma_f32_16x16x32_bf16, zero-conflict
// fragment pattern (r10/r11-verified, conflicts==0). Per tile: each thread
// computes 2 bases packs (~140 VALU) and ds_write_b128s them into the
// swizzled A buffer; B staged via global_load_lds. ds_reads of buf precede
// GENA writes to buf^1 in program order (no alias serialization). x values
// prefetched one tile ahead in registers. One vmcnt(0)+lgkmcnt(0)+barrier
// per K-tile. mode 0: bf16 split-K partials; mode 1: fp32 atomic fallback.
// ---------------------------------------------------------------------------
__device__ __forceinline__ void gload16(const void* g, void* l) {
    __builtin_amdgcn_global_load_lds((const __attribute__((address_space(1))) void*)g,
                                     (__attribute__((address_space(3))) void*)l,
                                     16, 0, 0);
}

#define MFMA(a, b, c) __builtin_amdgcn_mfma_f32_16x16x32_bf16((a), (b), (c), 0, 0, 0)

__global__ __launch_bounds__(1024, 1) void kan_gemm(const float* __restrict__ x,
                                                    const __hip_bfloat16* __restrict__ Bt,
                                                    __hip_bfloat16* __restrict__ Pb,
                                                    float* __restrict__ outC,
                                                    int mode) {
    __shared__ __hip_bfloat16 sA[2][256 * 64];   // 64 KiB
    __shared__ __hip_bfloat16 sB[2][256 * 64];   // 64 KiB

    const int tid  = threadIdx.x;
    const int orig = blockIdx.x;
    const int sb   = (orig & 7) * 32 + (orig >> 3);   // XCD chunk swizzle (256%8==0)
    const int bm   = sb >> 4;            // 0..15
    const int bn   = (sb >> 2) & 3;      // 0..3
    const int ks   = sb & 3;             // 0..3
    const int m0   = bm << 8;
    const int n0   = bn << 8;
    const int k0   = ks * KSL;

    // --- B staging (r11-identical): rows (t>>3)+r*128, 16B slot (t&7); linear
    // dest; source col pre-swizzled: LDS[row][s] = G[row][s ^ (row&7)].
    const int srow = tid >> 3;                                // 0..127
    const int scol = (((tid & 7) ^ (srow & 7)) << 3);         // elems
    const __hip_bfloat16* gB = Bt + (size_t)(n0 + srow) * KDIM + k0 + scol;
    const int t8 = tid * 8;

#define GLB(buf, kt, r) gload16(gB + (size_t)(kt) * BK + (size_t)((r) * 128) * KDIM, \
                                &sB[buf][(r) * 8192 + t8])

    // --- A generation (r13-verified addressing): thread -> row (tid>>2),
    // ii-pair ((tid&3)*2, +1); writes swizzled slots ii^ (row&7).
    const int grow = tid >> 2;                    // 0..255
    const int gii  = (tid & 3) << 1;              // 0,2,4,6
    const int grx  = grow & 7;
    const float2* gx = reinterpret_cast<const float2*>(
        x + (size_t)(m0 + grow) * INF + (k0 >> 3) + gii);   // + t*4 (float2)
    __hip_bfloat16* aRow = &sA[0][0] + grow * 64;           // + buf*16384

#define GENA(buf, xv2) do {                                                        \
        ushort8 p0 = bases8_fast((xv2).x);                                         \
        ushort8 p1 = bases8_fast((xv2).y);                                         \
        *reinterpret_cast<ushort8*>(aRow + (buf) * 16384 + (((gii    ) ^ grx) << 3)) = p0; \
        *reinterpret_cast<ushort8*>(aRow + (buf) * 16384 + (((gii + 1) ^ grx) << 3)) = p1; \
    } while (0)

    // compute: wave w -> rows [(w>>2)*64,+64), cols [(w&3)*64,+64)
    const int w    = tid >> 6;
    const int lane = tid & 63;
    const int wr   = w >> 2;             // 0..3
    const int wc   = w & 3;              // 0..3
    const int lr   = lane & 15;
    const int lk   = lane >> 4;          // 0..3
    const int ar0  = (wr << 6) + lr;     // + fi*16
    const int br0  = (wc << 6) + lr;     // + fj*16
    const int rx   = lr & 7;             // read-side XOR (row&7)

    f32x4 acc[4][4];
#pragma unroll
    for (int i = 0; i < 4; ++i)
#pragma unroll
        for (int j = 0; j < 4; ++j)
            acc[i][j] = (f32x4){0.0f, 0.0f, 0.0f, 0.0f};

    // --- prologue: stage B tile 0, generate A tile 0, prefetch x tile 1 ---
    GLB(0, 0, 0); GLB(0, 0, 1);
    float2 xcur = gx[0];
    GENA(0, xcur);
    float2 xnext = (NT > 1) ? gx[4] : xcur;
    asm volatile("s_waitcnt vmcnt(0) lgkmcnt(0)" ::: "memory");
    __builtin_amdgcn_s_barrier();

#pragma unroll 1
    for (int t = 0; t < NT; ++t) {
        const int buf = t & 1;
        const __hip_bfloat16* tA = &sA[buf][0];
        const __hip_bfloat16* tB = &sB[buf][0];

        // stage B(t+1) early (async DMA), pinned at loop top
        if (t + 1 < NT) {
            GLB(buf ^ 1, t + 1, 0); GLB(buf ^ 1, t + 1, 1);
        }
        __builtin_amdgcn_sched_barrier(0);

        // read ALL fragments of tile t (buf) BEFORE any write to buf^1
        short8 af[2][4], bf[2][4];
#pragma unroll
        for (int kk = 0; kk < 2; ++kk) {
            const int ph = (((kk << 2) | lk) ^ rx) << 3;
#pragma unroll
            for (int fi = 0; fi < 4; ++fi)
                af[kk][fi] = *reinterpret_cast<const short8*>(tA + (ar0 + fi * 16) * BK + ph);
#pragma unroll
            for (int fj = 0; fj < 4; ++fj)
                bf[kk][fj] = *reinterpret_cast<const short8*>(tB + (br0 + fj * 16) * BK + ph);
        }

        // generate A(t+1) into buf^1 (VALU + 2 ds_writes; interleaves w/ MFMAs)
        if (t + 1 < NT) GENA(buf ^ 1, xnext);
        if (t + 2 < NT) xnext = gx[(size_t)(t + 2) * 4];   // issue x-load early

        // MFMA body: 32 x mfma_f32_16x16x32_bf16
#pragma unroll
        for (int kk = 0; kk < 2; ++kk)
#pragma unroll
            for (int fi = 0; fi < 4; ++fi)
#pragma unroll
                for (int fj = 0; fj < 4; ++fj)
                    acc[fi][fj] = MFMA(af[kk][fi], bf[kk][fj], acc[fi][fj]);

        // --- epoch boundary: B staging + A ds_writes committed ---
        asm volatile("s_waitcnt vmcnt(0) lgkmcnt(0)" ::: "memory");
        __builtin_amdgcn_s_barrier();
    }
#undef GLB
#undef GENA

    // --- epilogue: 16x16 C/D layout: col = lane&15, row = (lane>>4)*4 + reg ---
    if (mode == 0) {
        __hip_bfloat16* dst = Pb + (size_t)ks * BATCH * OUTF;
#pragma unroll
        for (int fi = 0; fi < 4; ++fi) {
#pragma unroll
            for (int fj = 0; fj < 4; ++fj) {
                __hip_bfloat16* cp = dst
                    + (size_t)(m0 + (wr << 6) + fi * 16 + lk * 4) * OUTF
                    + (n0 + (wc << 6) + fj * 16 + lr);
#pragma unroll
                for (int r = 0; r < 4; ++r)
                    cp[(size_t)r * OUTF] = __float2bfloat16(acc[fi][fj][r]);
            }
        }
    } else {
#pragma unroll
        for (int fi = 0; fi < 4; ++fi) {
#pragma unroll
            for (int fj = 0; fj < 4; ++fj) {
                float* cp = outC + (size_t)(m0 + (wr << 6) + fi * 16 + lk * 4) * OUTF
                                 + (n0 + (wc << 6) + fj * 16 + lr);
#pragma unroll
                for (int r = 0; r < 4; ++r)
                    atomicAdd(cp + (size_t)r * OUTF, acc[fi][fj][r]);
            }
        }
    }
}

// ---------------------------------------------------------------------------
// Kernel 3: split-K reduce  out = sum of 4 bf16 partials (fp32 accumulate).
// ---------------------------------------------------------------------------
__global__ __launch_bounds__(256) void kan_reduce(const ushort8* __restrict__ Pb,
                                                  f32x4* __restrict__ out) {
    size_t i = (size_t)blockIdx.x * 256 + threadIdx.x;   // per 8 elems
    const size_t stride = (size_t)BATCH * OUTF / 8;
    ushort8 p0 = Pb[i];
    ushort8 p1 = Pb[i + stride];
    ushort8 p2 = Pb[i + 2 * stride];
    ushort8 p3 = Pb[i + 3 * stride];

    f32x4 lo, hi;
#pragma unroll
    for (int e = 0; e < 8; ++e) {
        union { unsigned int u; float f; } c0, c1, c2, c3;
        c0.u = (unsigned int)p0[e] << 16;
        c1.u = (unsigned int)p1[e] << 16;
        c2.u = (unsigned int)p2[e] << 16;
        c3.u = (unsigned int)p3[e] << 16;
        float s = (c0.f + c1.f) + (c2.f + c3.f);
        if (e < 4) lo[e] = s; else hi[e - 4] = s;
    }
    out[i * 2]     = lo;
    out[i * 2 + 1] = hi;
}

// ---------------------------------------------------------------------------
extern "C" void kernel_launch(void* const* d_in, const int* in_sizes, int n_in,
                              void* d_out, int out_size, void* d_ws, size_t ws_size,
                              hipStream_t stream) {
    const float* x = (const float*)d_in[0];       // (4096, 1024) fp32
    const float* w = (const float*)d_in[1];       // (1024, 1024, 8) fp32
    float* out = (float*)d_out;                   // (4096, 1024) fp32

    const size_t offP  = (size_t)OUTF * KDIM * 2;              // Wbf: 16 MiB
    const size_t needP = offP + (size_t)KS * BATCH * OUTF * 2; // +32 MiB bf16 partials

    __hip_bfloat16* Wbf = (__hip_bfloat16*)d_ws;
    __hip_bfloat16* Pb  = (__hip_bfloat16*)((char*)d_ws + offP);
    const bool partials = (ws_size >= needP);

    kan_wconv<<<(OUTF * KDIM / 8) / 256, 256, 0, stream>>>((const f32x4*)w, (short8*)Wbf);

    const int grid = (BATCH / 256) * (OUTF / 256) * KS;     // 256
    if (partials) {
        kan_gemm<<<grid, 1024, 0, stream>>>(x, Wbf, Pb, out, 0);
        kan_reduce<<<(BATCH * OUTF / 8) / 256, 256, 0, stream>>>((const ushort8*)Pb, (f32x4*)out);
    } else {
        hipMemsetAsync(out, 0, (size_t)BATCH * OUTF * sizeof(float), stream);
        kan_gemm<<<grid, 1024, 0, stream>>>(x, Wbf, Pb, out, 1);
    }
}

// Round 15
// 113.591 us; speedup vs baseline: 3.4017x; 3.4017x over previous
//
#include <hip/hip_runtime.h>
#include <hip/hip_bf16.h>
#include <stdint.h>
#include <stddef.h>

#define BATCH 4096
#define INF   1024
#define OUTF  1024
#define KDIM  8192            // 1024 in-features * 8 spline bases
#define KS    4               // split-K factor
#define KSL   (KDIM / KS)     // 2048 per slice
#define BK    64
#define NT    (KSL / BK)      // 32 K-tiles per block

typedef __attribute__((ext_vector_type(8)))  short           short8;
typedef __attribute__((ext_vector_type(8)))  unsigned short  ushort8;
typedef __attribute__((ext_vector_type(4)))  float           f32x4;

// ---------------------------------------------------------------------------
// Fast closed-form cubic B-spline bases (uniform knots, gap 0.4, range
// [-2.2,2.2)). Verified vs reference in r14 (absmax 0.0625, identical).
// ~40 VALU ops. Out-of-range x -> all zero via the placement chain.
// ---------------------------------------------------------------------------
__device__ __forceinline__ ushort8 bases8_fast(float xv) {
    const float X  = (xv + 2.2f) * 2.5f;      // cell space: knot(j) at X=j
    const float cf = floorf(X);
    const float t  = X - cf;                  // local coordinate in cell
    const int   c  = (int)cf;
    const float s  = 1.0f - t;
    const float t2 = t * t;
    const float w0 = s * s * s * (1.0f / 6.0f);
    const float w3 = t2 * t * (1.0f / 6.0f);
    const float w1 = (0.5f * t - 1.0f) * t2 + (2.0f / 3.0f);   // (3t^3-6t^2+4)/6
    const float w2 = 1.0f - w0 - w1 - w3;     // exact partition of unity

    __hip_bfloat16 h0 = __float2bfloat16(w0);
    __hip_bfloat16 h1 = __float2bfloat16(w1);
    __hip_bfloat16 h2 = __float2bfloat16(w2);
    __hip_bfloat16 h3 = __float2bfloat16(w3);
    const unsigned short u0 = *reinterpret_cast<unsigned short*>(&h0);
    const unsigned short u1 = *reinterpret_cast<unsigned short*>(&h1);
    const unsigned short u2 = *reinterpret_cast<unsigned short*>(&h2);
    const unsigned short u3 = *reinterpret_cast<unsigned short*>(&h3);

    const int i0 = c - 3;                     // first nonzero basis index
    union { ushort8 v; unsigned short u[8]; } pk;
#pragma unroll
    for (int g = 0; g < 8; ++g) {
        unsigned short v = 0;
        v = (i0 == g    ) ? u0 : v;
        v = (i0 == g - 1) ? u1 : v;
        v = (i0 == g - 2) ? u2 : v;
        v = (i0 == g - 3) ? u3 : v;
        pk.u[g] = v;
    }
    return pk.v;
}

// ---------------------------------------------------------------------------
// Kernel 1: weight fp32 -> bf16 (B^T row-major over k = i*8+g already).
// ---------------------------------------------------------------------------
__global__ __launch_bounds__(256) void kan_wconv(const f32x4* __restrict__ w,
                                                 short8* __restrict__ Wb) {
    size_t idx = (size_t)blockIdx.x * 256 + threadIdx.x;
    f32x4 a = w[idx * 2];
    f32x4 c = w[idx * 2 + 1];
    float t[8] = {a[0], a[1], a[2], a[3], c[0], c[1], c[2], c[3]};
    union { short8 v; unsigned short u[8]; } pk;
#pragma unroll
    for (int g = 0; g < 8; ++g) {
        __hip_bfloat16 h = __float2bfloat16(t[g]);
        pk.u[g] = *reinterpret_cast<unsigned short*>(&h);
    }
    Wb[idx] = pk.v;
}

// ---------------------------------------------------------------------------
// Kernel 2: FUSED bases + bf16 GEMM. r11's exact loop body (per-kk fragment
// reads -> no spill; r14's all-frags hoist DID spill) + per-tile A generation
// with bases8_fast (~90 VALU inst/thread/tile). 256x256 tile, BK=64,
// split-K=4, double-buffer (128 KiB), 1024 threads = 16 waves (4Mx4N,
// 64x64/wave), mfma_f32_16x16x32_bf16, zero-conflict swizzle (r10-verified).
// One vmcnt(0)+lgkmcnt(0)+barrier per K-tile.
// mode 0: bf16 split-K partials; mode 1: fp32 atomic fallback.
// ---------------------------------------------------------------------------
__device__ __forceinline__ void gload16(const void* g, void* l) {
    __builtin_amdgcn_global_load_lds((const __attribute__((address_space(1))) void*)g,
                                     (__attribute__((address_space(3))) void*)l,
                                     16, 0, 0);
}

#define MFMA(a, b, c) __builtin_amdgcn_mfma_f32_16x16x32_bf16((a), (b), (c), 0, 0, 0)

__global__ __launch_bounds__(1024, 1) void kan_gemm(const float* __restrict__ x,
                                                    const __hip_bfloat16* __restrict__ Bt,
                                                    __hip_bfloat16* __restrict__ Pb,
                                                    float* __restrict__ outC,
                                                    int mode) {
    __shared__ __hip_bfloat16 sA[2][256 * 64];   // 64 KiB
    __shared__ __hip_bfloat16 sB[2][256 * 64];   // 64 KiB

    const int tid  = threadIdx.x;
    const int orig = blockIdx.x;
    const int sb   = (orig & 7) * 32 + (orig >> 3);   // XCD chunk swizzle (256%8==0)
    const int bm   = sb >> 4;            // 0..15
    const int bn   = (sb >> 2) & 3;      // 0..3
    const int ks   = sb & 3;             // 0..3
    const int m0   = bm << 8;
    const int n0   = bn << 8;
    const int k0   = ks * KSL;

    // --- B staging (r11-identical): rows (t>>3)+r*128, 16B slot (t&7); linear
    // dest; source col pre-swizzled: LDS[row][s] = G[row][s ^ (row&7)].
    const int srow = tid >> 3;                                // 0..127
    const int scol = (((tid & 7) ^ (srow & 7)) << 3);         // elems
    const __hip_bfloat16* gB = Bt + (size_t)(n0 + srow) * KDIM + k0 + scol;
    const int t8 = tid * 8;

#define GLB(buf, kt, r) gload16(gB + (size_t)(kt) * BK + (size_t)((r) * 128) * KDIM, \
                                &sB[buf][(r) * 8192 + t8])

    // --- A generation (r13-verified addressing): thread -> row (tid>>2),
    // ii-pair ((tid&3)*2, +1); writes swizzled slots ii ^ (row&7).
    const int grow = tid >> 2;                    // 0..255
    const int gii  = (tid & 3) << 1;              // 0,2,4,6
    const int grx  = grow & 7;
    const float2* gx = reinterpret_cast<const float2*>(
        x + (size_t)(m0 + grow) * INF + (k0 >> 3) + gii);   // + t*4 (float2)
    __hip_bfloat16* aRow = &sA[0][0] + grow * 64;           // + buf*16384

#define GENA(buf, xv2) do {                                                        \
        ushort8 p0 = bases8_fast((xv2).x);                                         \
        ushort8 p1 = bases8_fast((xv2).y);                                         \
        *reinterpret_cast<ushort8*>(aRow + (buf) * 16384 + (((gii    ) ^ grx) << 3)) = p0; \
        *reinterpret_cast<ushort8*>(aRow + (buf) * 16384 + (((gii + 1) ^ grx) << 3)) = p1; \
    } while (0)

    // compute: wave w -> rows [(w>>2)*64,+64), cols [(w&3)*64,+64)
    const int w    = tid >> 6;
    const int lane = tid & 63;
    const int wr   = w >> 2;             // 0..3
    const int wc   = w & 3;              // 0..3
    const int lr   = lane & 15;
    const int lk   = lane >> 4;          // 0..3
    const int ar0  = (wr << 6) + lr;     // + fi*16
    const int br0  = (wc << 6) + lr;     // + fj*16
    const int rx   = lr & 7;             // read-side XOR (row&7)

    f32x4 acc[4][4];
#pragma unroll
    for (int i = 0; i < 4; ++i)
#pragma unroll
        for (int j = 0; j < 4; ++j)
            acc[i][j] = (f32x4){0.0f, 0.0f, 0.0f, 0.0f};

    // --- prologue: stage B tile 0, generate A tile 0, prefetch x tile 1 ---
    GLB(0, 0, 0); GLB(0, 0, 1);
    float2 xcur = gx[0];
    GENA(0, xcur);
    float2 xnext = (NT > 1) ? gx[4] : xcur;
    asm volatile("s_waitcnt vmcnt(0) lgkmcnt(0)" ::: "memory");
    __builtin_amdgcn_s_barrier();

#pragma unroll 1
    for (int t = 0; t < NT; ++t) {
        const int buf = t & 1;
        const __hip_bfloat16* tA = &sA[buf][0];
        const __hip_bfloat16* tB = &sB[buf][0];

        // stage B(t+1) early (async DMA), pinned at loop top
        if (t + 1 < NT) {
            GLB(buf ^ 1, t + 1, 0); GLB(buf ^ 1, t + 1, 1);
        }
        __builtin_amdgcn_sched_barrier(0);

        // epoch body (r11-identical, per-kk reads -> no spill):
        // 2 kk steps; per step 8 ds_read_b128 + 16 MFMA(16x16x32).
#pragma unroll
        for (int kk = 0; kk < 2; ++kk) {
            const int ph = (((kk << 2) | lk) ^ rx) << 3;   // elem offset in row
            short8 af[4], bf[4];
#pragma unroll
            for (int fi = 0; fi < 4; ++fi)
                af[fi] = *reinterpret_cast<const short8*>(tA + (ar0 + fi * 16) * BK + ph);
#pragma unroll
            for (int fj = 0; fj < 4; ++fj)
                bf[fj] = *reinterpret_cast<const short8*>(tB + (br0 + fj * 16) * BK + ph);
#pragma unroll
            for (int fi = 0; fi < 4; ++fi)
#pragma unroll
                for (int fj = 0; fj < 4; ++fj)
                    acc[fi][fj] = MFMA(af[fi], bf[fj], acc[fi][fj]);
        }

        // generate A(t+1) into buf^1 (VALU + 2 ds_writes; different buffer ->
        // no hazard with this tile's reads; compiler interleaves with MFMAs)
        if (t + 1 < NT) GENA(buf ^ 1, xnext);
        if (t + 2 < NT) xnext = gx[(size_t)(t + 2) * 4];   // issue x-load early

        // --- epoch boundary: B staging + A ds_writes committed ---
        asm volatile("s_waitcnt vmcnt(0) lgkmcnt(0)" ::: "memory");
        __builtin_amdgcn_s_barrier();
    }
#undef GLB
#undef GENA

    // --- epilogue: 16x16 C/D layout: col = lane&15, row = (lane>>4)*4 + reg ---
    if (mode == 0) {
        __hip_bfloat16* dst = Pb + (size_t)ks * BATCH * OUTF;
#pragma unroll
        for (int fi = 0; fi < 4; ++fi) {
#pragma unroll
            for (int fj = 0; fj < 4; ++fj) {
                __hip_bfloat16* cp = dst
                    + (size_t)(m0 + (wr << 6) + fi * 16 + lk * 4) * OUTF
                    + (n0 + (wc << 6) + fj * 16 + lr);
#pragma unroll
                for (int r = 0; r < 4; ++r)
                    cp[(size_t)r * OUTF] = __float2bfloat16(acc[fi][fj][r]);
            }
        }
    } else {
#pragma unroll
        for (int fi = 0; fi < 4; ++fi) {
#pragma unroll
            for (int fj = 0; fj < 4; ++fj) {
                float* cp = outC + (size_t)(m0 + (wr << 6) + fi * 16 + lk * 4) * OUTF
                                 + (n0 + (wc << 6) + fj * 16 + lr);
#pragma unroll
                for (int r = 0; r < 4; ++r)
                    atomicAdd(cp + (size_t)r * OUTF, acc[fi][fj][r]);
            }
        }
    }
}

// ---------------------------------------------------------------------------
// Kernel 3: split-K reduce  out = sum of 4 bf16 partials (fp32 accumulate).
// ---------------------------------------------------------------------------
__global__ __launch_bounds__(256) void kan_reduce(const ushort8* __restrict__ Pb,
                                                  f32x4* __restrict__ out) {
    size_t i = (size_t)blockIdx.x * 256 + threadIdx.x;   // per 8 elems
    const size_t stride = (size_t)BATCH * OUTF / 8;
    ushort8 p0 = Pb[i];
    ushort8 p1 = Pb[i + stride];
    ushort8 p2 = Pb[i + 2 * stride];
    ushort8 p3 = Pb[i + 3 * stride];

    f32x4 lo, hi;
#pragma unroll
    for (int e = 0; e < 8; ++e) {
        union { unsigned int u; float f; } c0, c1, c2, c3;
        c0.u = (unsigned int)p0[e] << 16;
        c1.u = (unsigned int)p1[e] << 16;
        c2.u = (unsigned int)p2[e] << 16;
        c3.u = (unsigned int)p3[e] << 16;
        float s = (c0.f + c1.f) + (c2.f + c3.f);
        if (e < 4) lo[e] = s; else hi[e - 4] = s;
    }
    out[i * 2]     = lo;
    out[i * 2 + 1] = hi;
}

// ---------------------------------------------------------------------------
extern "C" void kernel_launch(void* const* d_in, const int* in_sizes, int n_in,
                              void* d_out, int out_size, void* d_ws, size_t ws_size,
                              hipStream_t stream) {
    const float* x = (const float*)d_in[0];       // (4096, 1024) fp32
    const float* w = (const float*)d_in[1];       // (1024, 1024, 8) fp32
    float* out = (float*)d_out;                   // (4096, 1024) fp32

    const size_t offP  = (size_t)OUTF * KDIM * 2;              // Wbf: 16 MiB
    const size_t needP = offP + (size_t)KS * BATCH * OUTF * 2; // +32 MiB bf16 partials

    __hip_bfloat16* Wbf = (__hip_bfloat16*)d_ws;
    __hip_bfloat16* Pb  = (__hip_bfloat16*)((char*)d_ws + offP);
    const bool partials = (ws_size >= needP);

    kan_wconv<<<(OUTF * KDIM / 8) / 256, 256, 0, stream>>>((const f32x4*)w, (short8*)Wbf);

    const int grid = (BATCH / 256) * (OUTF / 256) * KS;     // 256
    if (partials) {
        kan_gemm<<<grid, 1024, 0, stream>>>(x, Wbf, Pb, out, 0);
        kan_reduce<<<(BATCH * OUTF / 8) / 256, 256, 0, stream>>>((const ushort8*)Pb, (f32x4*)out);
    } else {
        hipMemsetAsync(out, 0, (size_t)BATCH * OUTF * sizeof(float), stream);
        kan_gemm<<<grid, 1024, 0, stream>>>(x, Wbf, Pb, out, 1);
    }
}

// Round 16
// 95.114 us; speedup vs baseline: 4.0625x; 1.1943x over previous
//
#include <hip/hip_runtime.h>
#include <hip/hip_bf16.h>
#include <stdint.h>
#include <stddef.h>

#define BATCH 4096
#define INF   1024
#define OUTF  1024
#define KDIM  8192            // 1024 in-features * 8 spline bases
#define KS    4               // split-K factor
#define KSL   (KDIM / KS)     // 2048 per slice
#define BK    64
#define NT    (KSL / BK)      // 32 K-tiles per block

typedef __attribute__((ext_vector_type(8)))  short           short8;
typedef __attribute__((ext_vector_type(8)))  unsigned short  ushort8;
typedef __attribute__((ext_vector_type(4)))  float           f32x4;

__device__ constexpr float knot(int j) { return (float)(j - 3) * 0.4f - 1.0f; }

// ---------------------------------------------------------------------------
// Kernel 1: fused prep (r11-identical). Blocks [0,16384): B-spline bases
// (one thread per (b,i), 8 bf16 out). Blocks [16384,20480): weight fp32->bf16.
// ---------------------------------------------------------------------------
__global__ __launch_bounds__(256) void kan_prep(const float* __restrict__ x,
                                                short8* __restrict__ A,
                                                const f32x4* __restrict__ w,
                                                short8* __restrict__ Wb) {
    const int blk = blockIdx.x;
    if (blk < (BATCH * INF) / 256) {
        size_t idx = (size_t)blk * 256 + threadIdx.x;
        float xv = x[idx];

        float b[11];
#pragma unroll
        for (int j = 0; j < 11; ++j)
            b[j] = (xv >= knot(j) && xv < knot(j + 1)) ? 1.0f : 0.0f;

#pragma unroll
        for (int k = 1; k <= 3; ++k) {
#pragma unroll
            for (int j = 0; j + k < 11; ++j) {
                float left  = (xv - knot(j))         * (1.0f / (knot(j + k)     - knot(j)));
                float right = (knot(j + k + 1) - xv) * (1.0f / (knot(j + k + 1) - knot(j + 1)));
                b[j] = left * b[j] + right * b[j + 1];
            }
        }

        union { short8 v; unsigned short u[8]; } pk;
#pragma unroll
        for (int g = 0; g < 8; ++g) {
            __hip_bfloat16 h = __float2bfloat16(b[g]);
            pk.u[g] = *reinterpret_cast<unsigned short*>(&h);
        }
        A[idx] = pk.v;
    } else {
        size_t idx = (size_t)(blk - (BATCH * INF) / 256) * 256 + threadIdx.x;
        f32x4 a = w[idx * 2];
        f32x4 c = w[idx * 2 + 1];
        float t[8] = {a[0], a[1], a[2], a[3], c[0], c[1], c[2], c[3]};
        union { short8 v; unsigned short u[8]; } pk;
#pragma unroll
        for (int g = 0; g < 8; ++g) {
            __hip_bfloat16 h = __float2bfloat16(t[g]);
            pk.u[g] = *reinterpret_cast<unsigned short*>(&h);
        }
        Wb[idx] = pk.v;
    }
}

// ---------------------------------------------------------------------------
// Kernel 2: bf16 GEMM, 256x128 tile, BK=64, split-K=4, SINGLE-buffer LDS
// (48 KiB -> 2 blocks/CU; cross-block overlap hides stage-wait + barriers,
// m114). 512 threads = 8 waves (4M x 2N, 64x64/wave), mfma_f32_16x16x32_bf16,
// zero-conflict fragment pattern + both-sides XOR swizzle (r10/r11-verified,
// conflicts == 0). m97 2-barrier loop: stage -> vmcnt(0)+barrier -> compute
// -> barrier. mode 0: bf16 split-K partials; mode 1: fp32 atomic fallback.
// ---------------------------------------------------------------------------
__device__ __forceinline__ void gload16(const void* g, void* l) {
    __builtin_amdgcn_global_load_lds((const __attribute__((address_space(1))) void*)g,
                                     (__attribute__((address_space(3))) void*)l,
                                     16, 0, 0);
}

#define MFMA(a, b, c) __builtin_amdgcn_mfma_f32_16x16x32_bf16((a), (b), (c), 0, 0, 0)

__global__ __launch_bounds__(512, 4) void kan_gemm(const __hip_bfloat16* __restrict__ A,
                                                   const __hip_bfloat16* __restrict__ Bt,
                                                   __hip_bfloat16* __restrict__ Pb,
                                                   float* __restrict__ outC,
                                                   int mode) {
    __shared__ __hip_bfloat16 sA[256 * 64];   // 32 KiB
    __shared__ __hip_bfloat16 sB[128 * 64];   // 16 KiB

    const int tid  = threadIdx.x;
    const int orig = blockIdx.x;
    const int sb   = (orig & 7) * 64 + (orig >> 3);   // XCD chunk swizzle (512%8==0)
    const int bm   = sb >> 5;            // 0..15
    const int bn   = (sb >> 2) & 7;      // 0..7
    const int ks   = sb & 3;             // 0..3
    const int m0   = bm << 8;
    const int n0   = bn << 7;
    const int k0   = ks * KSL;

    // staging: thread t -> rows (t>>3)+r*64, 16B slot (t&7); LDS dest linear.
    // Source col pre-swizzled: LDS[row][s] = G[row][s ^ (row&7)]; (row&7)
    // invariant across r-steps (64 == 0 mod 8).
    const int srow = tid >> 3;                                // 0..63
    const int scol = (((tid & 7) ^ (srow & 7)) << 3);         // elems
    const __hip_bfloat16* gA = A  + (size_t)(m0 + srow) * KDIM + k0 + scol;
    const __hip_bfloat16* gB = Bt + (size_t)(n0 + srow) * KDIM + k0 + scol;
    const int t8 = tid * 8;

#define GLA(kt, r) gload16(gA + (size_t)(kt) * BK + (size_t)((r) * 64) * KDIM, \
                           &sA[(r) * 4096 + t8])
#define GLB(kt, r) gload16(gB + (size_t)(kt) * BK + (size_t)((r) * 64) * KDIM, \
                           &sB[(r) * 4096 + t8])

    // compute: wave w -> rows [(w>>1)*64,+64), cols [(w&1)*64,+64)
    const int w    = tid >> 6;
    const int lane = tid & 63;
    const int wr   = w >> 1;             // 0..3
    const int wc   = w & 1;              // 0..1
    const int lr   = lane & 15;
    const int lk   = lane >> 4;          // 0..3
    const int ar0  = (wr << 6) + lr;     // + fi*16
    const int br0  = (wc << 6) + lr;     // + fj*16
    const int rx   = lr & 7;             // read-side XOR (row&7)

    f32x4 acc[4][4];
#pragma unroll
    for (int i = 0; i < 4; ++i)
#pragma unroll
        for (int j = 0; j < 4; ++j)
            acc[i][j] = (f32x4){0.0f, 0.0f, 0.0f, 0.0f};

#pragma unroll 1
    for (int t = 0; t < NT; ++t) {
        // stage tile t (6 x 16B per thread); safe: all reads of tile t-1
        // completed before the end-of-iteration barrier below.
        GLA(t, 0); GLA(t, 1); GLA(t, 2); GLA(t, 3);
        GLB(t, 0); GLB(t, 1);
        asm volatile("s_waitcnt vmcnt(0)" ::: "memory");
        __builtin_amdgcn_s_barrier();

        // compute: 2 kk steps; per step 8 ds_read_b128 + 16 MFMA(16x16x32).
        // phys slot = (4kk+lk) ^ (lr&7) -> 0 conflicts (r10/r11-measured).
#pragma unroll
        for (int kk = 0; kk < 2; ++kk) {
            const int ph = (((kk << 2) | lk) ^ rx) << 3;   // elem offset in row
            short8 af[4], bf[4];
#pragma unroll
            for (int fi = 0; fi < 4; ++fi)
                af[fi] = *reinterpret_cast<const short8*>(sA + (ar0 + fi * 16) * BK + ph);
#pragma unroll
            for (int fj = 0; fj < 4; ++fj)
                bf[fj] = *reinterpret_cast<const short8*>(sB + (br0 + fj * 16) * BK + ph);
#pragma unroll
            for (int fi = 0; fi < 4; ++fi)
#pragma unroll
                for (int fj = 0; fj < 4; ++fj)
                    acc[fi][fj] = MFMA(af[fi], bf[fj], acc[fi][fj]);
        }

        // all reads of tile t done (consumed by MFMAs above) -> next stage safe
        __builtin_amdgcn_s_barrier();
    }
#undef GLA
#undef GLB

    // --- epilogue: 16x16 C/D layout: col = lane&15, row = (lane>>4)*4 + reg ---
    if (mode == 0) {
        __hip_bfloat16* dst = Pb + (size_t)ks * BATCH * OUTF;
#pragma unroll
        for (int fi = 0; fi < 4; ++fi) {
#pragma unroll
            for (int fj = 0; fj < 4; ++fj) {
                __hip_bfloat16* cp = dst
                    + (size_t)(m0 + (wr << 6) + fi * 16 + lk * 4) * OUTF
                    + (n0 + (wc << 6) + fj * 16 + lr);
#pragma unroll
                for (int r = 0; r < 4; ++r)
                    cp[(size_t)r * OUTF] = __float2bfloat16(acc[fi][fj][r]);
            }
        }
    } else {
#pragma unroll
        for (int fi = 0; fi < 4; ++fi) {
#pragma unroll
            for (int fj = 0; fj < 4; ++fj) {
                float* cp = outC + (size_t)(m0 + (wr << 6) + fi * 16 + lk * 4) * OUTF
                                 + (n0 + (wc << 6) + fj * 16 + lr);
#pragma unroll
                for (int r = 0; r < 4; ++r)
                    atomicAdd(cp + (size_t)r * OUTF, acc[fi][fj][r]);
            }
        }
    }
}

// ---------------------------------------------------------------------------
// Kernel 3: split-K reduce  out = sum of 4 bf16 partials (fp32 accumulate).
// ---------------------------------------------------------------------------
__global__ __launch_bounds__(256) void kan_reduce(const ushort8* __restrict__ Pb,
                                                  f32x4* __restrict__ out) {
    size_t i = (size_t)blockIdx.x * 256 + threadIdx.x;   // per 8 elems
    const size_t stride = (size_t)BATCH * OUTF / 8;
    ushort8 p0 = Pb[i];
    ushort8 p1 = Pb[i + stride];
    ushort8 p2 = Pb[i + 2 * stride];
    ushort8 p3 = Pb[i + 3 * stride];

    f32x4 lo, hi;
#pragma unroll
    for (int e = 0; e < 8; ++e) {
        union { unsigned int u; float f; } c0, c1, c2, c3;
        c0.u = (unsigned int)p0[e] << 16;
        c1.u = (unsigned int)p1[e] << 16;
        c2.u = (unsigned int)p2[e] << 16;
        c3.u = (unsigned int)p3[e] << 16;
        float s = (c0.f + c1.f) + (c2.f + c3.f);
        if (e < 4) lo[e] = s; else hi[e - 4] = s;
    }
    out[i * 2]     = lo;
    out[i * 2 + 1] = hi;
}

// ---------------------------------------------------------------------------
extern "C" void kernel_launch(void* const* d_in, const int* in_sizes, int n_in,
                              void* d_out, int out_size, void* d_ws, size_t ws_size,
                              hipStream_t stream) {
    const float* x = (const float*)d_in[0];       // (4096, 1024) fp32
    const float* w = (const float*)d_in[1];       // (1024, 1024, 8) fp32
    float* out = (float*)d_out;                   // (4096, 1024) fp32

    const size_t offW  = (size_t)BATCH * KDIM * 2;             // Abf: 64 MiB
    const size_t offP  = offW + (size_t)OUTF * KDIM * 2;       // Wbf: +16 MiB
    const size_t needP = offP + (size_t)KS * BATCH * OUTF * 2; // +32 MiB bf16 partials

    __hip_bfloat16* Abf = (__hip_bfloat16*)d_ws;
    __hip_bfloat16* Wbf = (__hip_bfloat16*)((char*)d_ws + offW);
    __hip_bfloat16* Pb  = (__hip_bfloat16*)((char*)d_ws + offP);
    const bool partials = (ws_size >= needP);

    const int prepGrid = (BATCH * INF) / 256 + (OUTF * KDIM / 8) / 256;  // 20480
    kan_prep<<<prepGrid, 256, 0, stream>>>(x, (short8*)Abf, (const f32x4*)w, (short8*)Wbf);

    const int grid = (BATCH / 256) * (OUTF / 128) * KS;     // 512 -> 2 blocks/CU
    if (partials) {
        kan_gemm<<<grid, 512, 0, stream>>>(Abf, Wbf, Pb, out, 0);
        kan_reduce<<<(BATCH * OUTF / 8) / 256, 256, 0, stream>>>((const ushort8*)Pb, (f32x4*)out);
    } else {
        hipMemsetAsync(out, 0, (size_t)BATCH * OUTF * sizeof(float), stream);
        kan_gemm<<<grid, 512, 0, stream>>>(Abf, Wbf, Pb, out, 1);
    }
}